// Round 2
// baseline (221.538 us; speedup 1.0000x reference)
//
#include <hip/hip_runtime.h>
#include <math.h>

#define BB 32
#define SS 8192
#define DD 512
#define D4 (DD / 4)   // 128
#define CHUNKS 64     // chunks per batch row
#define CHUNK 128     // slots per chunk (SS / CHUNKS)

static constexpr float AGE_PEN = 0.02f;
static constexpr float MIN_STR = 0.001f;
static constexpr float STR_BOOST = 0.5f;
static constexpr float RMS_EPS_F = 1e-6f;

__device__ inline float dot4(float4 a, float4 b) {
    return a.x * b.x + a.y * b.y + a.z * b.z + a.w * b.w;
}

// block reduction (4 waves, 256 threads)
__device__ inline float block_sum(float v, volatile float* red) {
    int tid = threadIdx.x, lane = tid & 63, wid = tid >> 6;
#pragma unroll
    for (int off = 32; off; off >>= 1) v += __shfl_xor(v, off);
    if (lane == 0) red[wid] = v;
    __syncthreads();
    float r = red[0] + red[1] + red[2] + red[3];
    __syncthreads();
    return r;
}

// ---- kernel 1 (fused): logits + unnormalized exp-weighted val accumulation ----
// grid = (CHUNKS, B), block = 256 (4 waves). One wave per slot iteration.
__global__ __launch_bounds__(256) void fused_kernel(
    const float4* __restrict__ keys, const float4* __restrict__ vals,
    const float* __restrict__ q, const float* __restrict__ age,
    const float* __restrict__ strength, float* __restrict__ logits,
    float4* __restrict__ partial, float* __restrict__ esum_partial) {
    __shared__ float4 racc[4 * D4];   // 8 KB
    __shared__ float rede[4];

    int chunk = blockIdx.x, b = blockIdx.y;
    int tid = threadIdx.x, wid = tid >> 6, lane = tid & 63;

    // per-wave redundant qn (q row is L1/L2-hot: 2 KB)
    const float4* q4 = (const float4*)q + b * D4;
    float4 q0 = q4[lane], q1 = q4[lane + 64];
    float qq = dot4(q0, q0) + dot4(q1, q1);
#pragma unroll
    for (int off = 32; off; off >>= 1) qq += __shfl_xor(qq, off);
    float qinv = 1.f / (sqrtf(qq) + 1e-6f);
    q0.x *= qinv; q0.y *= qinv; q0.z *= qinv; q0.w *= qinv;
    q1.x *= qinv; q1.y *= qinv; q1.z *= qinv; q1.w *= qinv;

    long long s0 = (long long)b * SS + chunk * CHUNK;
    float4 acc0 = {0.f, 0.f, 0.f, 0.f}, acc1 = {0.f, 0.f, 0.f, 0.f};
    float esum = 0.f;

#pragma unroll 2
    for (int s = wid; s < CHUNK; s += 4) {
        long long row = s0 + s;
        const float4* k = keys + row * D4;
        const float4* v = vals + row * D4;
        float4 k0 = k[lane], k1 = k[lane + 64];
        float4 v0 = v[lane], v1 = v[lane + 64];

        float kk = dot4(k0, k0) + dot4(k1, k1);
        float kq = dot4(k0, q0) + dot4(k1, q1);
#pragma unroll
        for (int off = 32; off; off >>= 1) {
            kk += __shfl_xor(kk, off);
            kq += __shfl_xor(kq, off);
        }
        float st = strength[row];
        float a = age[row];
        float lg = kq / (sqrtf(kk) + 1e-6f)
                 + STR_BOOST * logf(fminf(fmaxf(st, MIN_STR), 1e9f))
                 - AGE_PEN * a;
        if (!(st > MIN_STR)) lg -= 1000.f;
        if (lane == 0) logits[row] = lg;

        float e = expf(lg);   // logits <= 1, so no overflow; dead slots -> 0
        esum += e;
        acc0.x += e * v0.x; acc0.y += e * v0.y; acc0.z += e * v0.z; acc0.w += e * v0.w;
        acc1.x += e * v1.x; acc1.y += e * v1.y; acc1.z += e * v1.z; acc1.w += e * v1.w;
    }

    racc[wid * D4 + lane] = acc0;
    racc[wid * D4 + 64 + lane] = acc1;
    if (lane == 0) rede[wid] = esum;
    __syncthreads();

    if (tid < D4) {
        float4 a0 = racc[tid], a1 = racc[D4 + tid], a2 = racc[2 * D4 + tid], a3 = racc[3 * D4 + tid];
        float4 r;
        r.x = a0.x + a1.x + a2.x + a3.x;
        r.y = a0.y + a1.y + a2.y + a3.y;
        r.z = a0.z + a1.z + a2.z + a3.z;
        r.w = a0.w + a1.w + a2.w + a3.w;
        partial[((long long)b * CHUNKS + chunk) * D4 + tid] = r;
    } else if (tid == D4) {
        esum_partial[b * CHUNKS + chunk] = rede[0] + rede[1] + rede[2] + rede[3];
    }
}

// ---- kernel 2: reduce partials, normalize, RMSNorm; one block per b ----
__global__ __launch_bounds__(256) void reduce_rms_kernel(
    const float* __restrict__ partial, const float* __restrict__ esum_partial,
    const float* __restrict__ scale, float* __restrict__ readout,
    float* __restrict__ inv_esum) {
    __shared__ float red[4];
    int b = blockIdx.x, tid = threadIdx.x;

    const float* p = partial + (long long)b * CHUNKS * DD;
    float r0 = 0.f, r1 = 0.f;
#pragma unroll 4
    for (int c = 0; c < CHUNKS; c++) {
        r0 += p[c * DD + tid];
        r1 += p[c * DD + tid + 256];
    }
    float le = (tid < CHUNKS) ? esum_partial[b * CHUNKS + tid] : 0.f;
    float etot = block_sum(le, red);
    float inv_e = 1.f / etot;
    if (tid == 0) inv_esum[b] = inv_e;
    r0 *= inv_e;
    r1 *= inv_e;
    float ss = block_sum(r0 * r0 + r1 * r1, red);
    float rms = sqrtf(ss / (float)DD + RMS_EPS_F);
    float inv = 1.f / rms;
    readout[b * DD + tid] = r0 * inv * scale[tid];
    readout[b * DD + tid + 256] = r1 * inv * scale[tid + 256];
}

// ---- kernel 3: w = exp(logits) * inv_esum[b], vectorized float4 ----
__global__ __launch_bounds__(256) void w_kernel(const float4* __restrict__ logits,
                                                const float* __restrict__ inv_esum,
                                                float4* __restrict__ w) {
    int i4 = blockIdx.x * 256 + threadIdx.x;  // BB*SS/4 = 65536 elems
    int b = i4 >> 11;                         // (i4*4) / SS
    float inv = inv_esum[b];
    float4 lg = logits[i4];
    float4 r;
    r.x = expf(lg.x) * inv;
    r.y = expf(lg.y) * inv;
    r.z = expf(lg.z) * inv;
    r.w = expf(lg.w) * inv;
    w[i4] = r;
}

extern "C" void kernel_launch(void* const* d_in, const int* in_sizes, int n_in,
                              void* d_out, int out_size, void* d_ws, size_t ws_size,
                              hipStream_t stream) {
    const float* q        = (const float*)d_in[0];
    const float* keys     = (const float*)d_in[1];
    const float* vals     = (const float*)d_in[2];
    const float* age      = (const float*)d_in[3];
    const float* strength = (const float*)d_in[4];
    const float* scale    = (const float*)d_in[5];

    float* out = (float*)d_out;
    float* readout = out;                      // [B, D]   = 16384
    float* w       = out + BB * DD;            // [B, S]   = 262144
    float* logits  = out + BB * DD + BB * SS;  // [B, S]   = 262144

    float* ws = (float*)d_ws;
    float* partial      = ws;                              // B*CHUNKS*D = 1,048,576 floats
    float* esum_partial = ws + BB * CHUNKS * DD;           // B*CHUNKS = 2048
    float* inv_esum     = esum_partial + BB * CHUNKS;      // B = 32

    fused_kernel<<<dim3(CHUNKS, BB), 256, 0, stream>>>(
        (const float4*)keys, (const float4*)vals, q, age, strength,
        logits, (float4*)partial, esum_partial);
    reduce_rms_kernel<<<BB, 256, 0, stream>>>(partial, esum_partial, scale, readout, inv_esum);
    w_kernel<<<BB * SS / 4 / 256, 256, 0, stream>>>((const float4*)logits, inv_esum, (float4*)w);
}

// Round 3
// 206.739 us; speedup vs baseline: 1.0716x; 1.0716x over previous
//
#include <hip/hip_runtime.h>
#include <math.h>

#define BB 32
#define SS 8192
#define DD 512
#define D4 (DD / 4)   // 128
#define CHUNKS 64     // chunks per batch row
#define CHUNK 128     // slots per chunk (SS / CHUNKS)

static constexpr float AGE_PEN = 0.02f;
static constexpr float MIN_STR = 0.001f;
static constexpr float STR_BOOST = 0.5f;
static constexpr float RMS_EPS_F = 1e-6f;

__device__ inline float dot4(float4 a, float4 b) {
    return a.x * b.x + a.y * b.y + a.z * b.z + a.w * b.w;
}

// block reduction (4 waves, 256 threads)
__device__ inline float block_sum(float v, volatile float* red) {
    int tid = threadIdx.x, lane = tid & 63, wid = tid >> 6;
#pragma unroll
    for (int off = 32; off; off >>= 1) v += __shfl_xor(v, off);
    if (lane == 0) red[wid] = v;
    __syncthreads();
    float r = red[0] + red[1] + red[2] + red[3];
    __syncthreads();
    return r;
}

// ---- kernel 1 (fused, two-phase): keys pass -> e in LDS; vals pass -> acc ----
// grid = (CHUNKS, B), block = 256 (4 waves). One wave per slot iteration.
__global__ __launch_bounds__(256) void fused_kernel(
    const float4* __restrict__ keys, const float4* __restrict__ vals,
    const float* __restrict__ q, const float* __restrict__ age,
    const float* __restrict__ strength, float* __restrict__ logits,
    float4* __restrict__ partial, float* __restrict__ esum_partial) {
    __shared__ float4 racc[4 * D4];   // 8 KB
    __shared__ float e_sh[CHUNK];
    __shared__ float rede[4];

    int chunk = blockIdx.x, b = blockIdx.y;
    int tid = threadIdx.x, wid = tid >> 6, lane = tid & 63;

    // per-wave redundant qn (q row is 2 KB, L1-hot)
    const float4* q4 = (const float4*)q + b * D4;
    float4 q0 = q4[lane], q1 = q4[lane + 64];
    float qq = dot4(q0, q0) + dot4(q1, q1);
#pragma unroll
    for (int off = 32; off; off >>= 1) qq += __shfl_xor(qq, off);
    float qinv = 1.f / (sqrtf(qq) + 1e-6f);
    q0.x *= qinv; q0.y *= qinv; q0.z *= qinv; q0.w *= qinv;
    q1.x *= qinv; q1.y *= qinv; q1.z *= qinv; q1.w *= qinv;

    long long s0 = (long long)b * SS + chunk * CHUNK;

    // ---- phase 1: keys only -> logits, e ----
    float esum = 0.f;
#pragma unroll 2
    for (int s = wid; s < CHUNK; s += 4) {
        long long row = s0 + s;
        const float4* k = keys + row * D4;
        float4 k0 = k[lane], k1 = k[lane + 64];

        float kk = dot4(k0, k0) + dot4(k1, k1);
        float kq = dot4(k0, q0) + dot4(k1, q1);
#pragma unroll
        for (int off = 32; off; off >>= 1) {
            kk += __shfl_xor(kk, off);
            kq += __shfl_xor(kq, off);
        }
        float st = strength[row];
        float a = age[row];
        float lg = kq / (sqrtf(kk) + 1e-6f)
                 + STR_BOOST * logf(fminf(fmaxf(st, MIN_STR), 1e9f))
                 - AGE_PEN * a;
        if (!(st > MIN_STR)) lg -= 1000.f;
        float e = expf(lg);   // logits <= 1: no overflow; dead slots underflow to 0
        esum += e;
        if (lane == 0) {
            logits[row] = lg;
            e_sh[s] = e;
        }
    }
    if (lane == 0) rede[wid] = esum;
    __syncthreads();

    // ---- phase 2: vals only, pure streaming FMA ----
    float4 acc0 = {0.f, 0.f, 0.f, 0.f}, acc1 = {0.f, 0.f, 0.f, 0.f};
#pragma unroll 4
    for (int s = wid; s < CHUNK; s += 4) {
        long long row = s0 + s;
        const float4* v = vals + row * D4;
        float e = e_sh[s];
        float4 v0 = v[lane], v1 = v[lane + 64];
        acc0.x += e * v0.x; acc0.y += e * v0.y; acc0.z += e * v0.z; acc0.w += e * v0.w;
        acc1.x += e * v1.x; acc1.y += e * v1.y; acc1.z += e * v1.z; acc1.w += e * v1.w;
    }

    racc[wid * D4 + lane] = acc0;
    racc[wid * D4 + 64 + lane] = acc1;
    __syncthreads();

    if (tid < D4) {
        float4 a0 = racc[tid], a1 = racc[D4 + tid], a2 = racc[2 * D4 + tid], a3 = racc[3 * D4 + tid];
        float4 r;
        r.x = a0.x + a1.x + a2.x + a3.x;
        r.y = a0.y + a1.y + a2.y + a3.y;
        r.z = a0.z + a1.z + a2.z + a3.z;
        r.w = a0.w + a1.w + a2.w + a3.w;
        partial[((long long)b * CHUNKS + chunk) * D4 + tid] = r;
    } else if (tid == D4) {
        esum_partial[b * CHUNKS + chunk] = rede[0] + rede[1] + rede[2] + rede[3];
    }
}

// ---- kernel 2: reduce partials, normalize, RMSNorm; one block per b ----
__global__ __launch_bounds__(256) void reduce_rms_kernel(
    const float* __restrict__ partial, const float* __restrict__ esum_partial,
    const float* __restrict__ scale, float* __restrict__ readout,
    float* __restrict__ inv_esum) {
    __shared__ float red[4];
    int b = blockIdx.x, tid = threadIdx.x;

    const float* p = partial + (long long)b * CHUNKS * DD;
    float r0 = 0.f, r1 = 0.f;
#pragma unroll 4
    for (int c = 0; c < CHUNKS; c++) {
        r0 += p[c * DD + tid];
        r1 += p[c * DD + tid + 256];
    }
    float le = (tid < CHUNKS) ? esum_partial[b * CHUNKS + tid] : 0.f;
    float etot = block_sum(le, red);
    float inv_e = 1.f / etot;
    if (tid == 0) inv_esum[b] = inv_e;
    r0 *= inv_e;
    r1 *= inv_e;
    float ss = block_sum(r0 * r0 + r1 * r1, red);
    float rms = sqrtf(ss / (float)DD + RMS_EPS_F);
    float inv = 1.f / rms;
    readout[b * DD + tid] = r0 * inv * scale[tid];
    readout[b * DD + tid + 256] = r1 * inv * scale[tid + 256];
}

// ---- kernel 3: w = exp(logits) * inv_esum[b], vectorized float4 ----
__global__ __launch_bounds__(256) void w_kernel(const float4* __restrict__ logits,
                                                const float* __restrict__ inv_esum,
                                                float4* __restrict__ w) {
    int i4 = blockIdx.x * 256 + threadIdx.x;  // BB*SS/4 = 65536 elems
    int b = i4 >> 11;                         // (i4*4) / SS
    float inv = inv_esum[b];
    float4 lg = logits[i4];
    float4 r;
    r.x = expf(lg.x) * inv;
    r.y = expf(lg.y) * inv;
    r.z = expf(lg.z) * inv;
    r.w = expf(lg.w) * inv;
    w[i4] = r;
}

extern "C" void kernel_launch(void* const* d_in, const int* in_sizes, int n_in,
                              void* d_out, int out_size, void* d_ws, size_t ws_size,
                              hipStream_t stream) {
    const float* q        = (const float*)d_in[0];
    const float* keys     = (const float*)d_in[1];
    const float* vals     = (const float*)d_in[2];
    const float* age      = (const float*)d_in[3];
    const float* strength = (const float*)d_in[4];
    const float* scale    = (const float*)d_in[5];

    float* out = (float*)d_out;
    float* readout = out;                      // [B, D]   = 16384
    float* w       = out + BB * DD;            // [B, S]   = 262144
    float* logits  = out + BB * DD + BB * SS;  // [B, S]   = 262144

    float* ws = (float*)d_ws;
    float* partial      = ws;                              // B*CHUNKS*D = 1,048,576 floats
    float* esum_partial = ws + BB * CHUNKS * DD;           // B*CHUNKS = 2048
    float* inv_esum     = esum_partial + BB * CHUNKS;      // B = 32

    fused_kernel<<<dim3(CHUNKS, BB), 256, 0, stream>>>(
        (const float4*)keys, (const float4*)vals, q, age, strength,
        logits, (float4*)partial, esum_partial);
    reduce_rms_kernel<<<BB, 256, 0, stream>>>(partial, esum_partial, scale, readout, inv_esum);
    w_kernel<<<BB * SS / 4 / 256, 256, 0, stream>>>((const float4*)logits, inv_esum, (float4*)w);
}

// Round 4
// 201.738 us; speedup vs baseline: 1.0981x; 1.0248x over previous
//
#include <hip/hip_runtime.h>
#include <math.h>

#define BB 32
#define SS 8192
#define DD 512
#define D4 (DD / 4)   // 128
#define CHUNKS 64     // chunks per batch row
#define CHUNK 128     // slots per chunk (SS / CHUNKS)

static constexpr float AGE_PEN = 0.02f;
static constexpr float MIN_STR = 0.001f;
static constexpr float STR_BOOST = 0.5f;
static constexpr float RMS_EPS_F = 1e-6f;

__device__ inline float dot4(float4 a, float4 b) {
    return a.x * b.x + a.y * b.y + a.z * b.z + a.w * b.w;
}

// block reduction (expects 256-thread block = 4 waves)
__device__ inline float block_sum(float v, volatile float* red) {
    int tid = threadIdx.x, lane = tid & 63, wid = tid >> 6;
#pragma unroll
    for (int off = 32; off; off >>= 1) v += __shfl_xor(v, off);
    if (lane == 0) red[wid] = v;
    __syncthreads();
    float r = red[0] + red[1] + red[2] + red[3];
    __syncthreads();
    return r;
}

// ---- kernel 1: keys stream -> logits + e (= unnormalized w). wave/row, no LDS, no syncs ----
__global__ __launch_bounds__(256) void logits_e_kernel(
    const float4* __restrict__ keys, const float* __restrict__ q,
    const float* __restrict__ age, const float* __restrict__ strength,
    float* __restrict__ logits, float* __restrict__ e_out) {
    int wid = threadIdx.x >> 6, lane = threadIdx.x & 63;
    int row = blockIdx.x * 4 + wid;           // < BB*SS
    int b = row >> 13;                        // row / SS

    // per-wave qn in registers (q row = 2 KB, L1/L2-hot)
    const float4* q4 = (const float4*)q + b * D4;
    float4 q0 = q4[lane], q1 = q4[lane + 64];
    float qq = dot4(q0, q0) + dot4(q1, q1);
#pragma unroll
    for (int off = 32; off; off >>= 1) qq += __shfl_xor(qq, off);
    float qinv = 1.f / (sqrtf(qq) + 1e-6f);

    const float4* k = keys + (long long)row * D4;
    float4 k0 = k[lane], k1 = k[lane + 64];
    float kk = dot4(k0, k0) + dot4(k1, k1);
    float kq = dot4(k0, q0) + dot4(k1, q1);
#pragma unroll
    for (int off = 32; off; off >>= 1) {
        kk += __shfl_xor(kk, off);
        kq += __shfl_xor(kq, off);
    }
    if (lane == 0) {
        float st = strength[row];
        float a = age[row];
        float sim = kq * qinv / (sqrtf(kk) + 1e-6f);
        float lg = sim + STR_BOOST * logf(fminf(fmaxf(st, MIN_STR), 1e9f)) - AGE_PEN * a;
        if (!(st > MIN_STR)) lg -= 1000.f;
        logits[row] = lg;
        e_out[row] = expf(lg);   // logits <= 1: no overflow; dead slots underflow to 0
    }
}

// ---- kernel 2: vals stream -> partial weighted sums + esum partials ----
// grid = (CHUNKS, B), block = 128 threads (one float4 column each)
__global__ __launch_bounds__(128) void wsum_kernel(
    const float4* __restrict__ vals, const float* __restrict__ e,
    float4* __restrict__ partial, float* __restrict__ esum_partial) {
    __shared__ float sw[CHUNK];
    __shared__ float rede[2];
    int chunk = blockIdx.x, b = blockIdx.y, tid = threadIdx.x;
    int s0 = chunk * CHUNK;
    float my_e = e[b * SS + s0 + tid];
    sw[tid] = my_e;
    __syncthreads();

    const float4* vbase = vals + ((long long)b * SS + s0) * D4 + tid;
    float4 acc = {0.f, 0.f, 0.f, 0.f};
#pragma unroll 4
    for (int s = 0; s < CHUNK; s++) {
        float4 v = vbase[(long long)s * D4];
        float ww = sw[s];
        acc.x += ww * v.x;
        acc.y += ww * v.y;
        acc.z += ww * v.z;
        acc.w += ww * v.w;
    }
    partial[((long long)b * CHUNKS + chunk) * D4 + tid] = acc;

    // per-chunk esum (after the streaming loop; 2 waves)
    float t = my_e;
#pragma unroll
    for (int off = 32; off; off >>= 1) t += __shfl_xor(t, off);
    if ((tid & 63) == 0) rede[tid >> 6] = t;
    __syncthreads();
    if (tid == 0) esum_partial[b * CHUNKS + chunk] = rede[0] + rede[1];
}

// ---- kernel 3: reduce partials + esum, RMSNorm; one block per b ----
__global__ __launch_bounds__(256) void reduce_rms_kernel(
    const float* __restrict__ partial, const float* __restrict__ esum_partial,
    const float* __restrict__ scale, float* __restrict__ readout,
    float* __restrict__ inv_esum) {
    __shared__ float red[4];
    int b = blockIdx.x, tid = threadIdx.x;

    const float* p = partial + (long long)b * CHUNKS * DD;
    float r0 = 0.f, r1 = 0.f;
#pragma unroll 4
    for (int c = 0; c < CHUNKS; c++) {
        r0 += p[c * DD + tid];
        r1 += p[c * DD + tid + 256];
    }
    float le = (tid < CHUNKS) ? esum_partial[b * CHUNKS + tid] : 0.f;
    float etot = block_sum(le, red);
    float inv_e = 1.f / etot;
    if (tid == 0) inv_esum[b] = inv_e;
    r0 *= inv_e;
    r1 *= inv_e;
    float ss = block_sum(r0 * r0 + r1 * r1, red);
    float rms = sqrtf(ss / (float)DD + RMS_EPS_F);
    float inv = 1.f / rms;
    readout[b * DD + tid] = r0 * inv * scale[tid];
    readout[b * DD + tid + 256] = r1 * inv * scale[tid + 256];
}

// ---- kernel 4: w *= inv_esum[b], in place, vectorized ----
__global__ __launch_bounds__(256) void w_scale_kernel(float4* __restrict__ w,
                                                      const float* __restrict__ inv_esum) {
    int i4 = blockIdx.x * 256 + threadIdx.x;  // BB*SS/4 = 65536 elems
    int b = i4 >> 11;                         // (i4*4) / SS
    float inv = inv_esum[b];
    float4 v = w[i4];
    v.x *= inv; v.y *= inv; v.z *= inv; v.w *= inv;
    w[i4] = v;
}

extern "C" void kernel_launch(void* const* d_in, const int* in_sizes, int n_in,
                              void* d_out, int out_size, void* d_ws, size_t ws_size,
                              hipStream_t stream) {
    const float* q        = (const float*)d_in[0];
    const float* keys     = (const float*)d_in[1];
    const float* vals     = (const float*)d_in[2];
    const float* age      = (const float*)d_in[3];
    const float* strength = (const float*)d_in[4];
    const float* scale    = (const float*)d_in[5];

    float* out = (float*)d_out;
    float* readout = out;                      // [B, D]   = 16384
    float* w       = out + BB * DD;            // [B, S]   = 262144 (holds e, then scaled in place)
    float* logits  = out + BB * DD + BB * SS;  // [B, S]   = 262144

    float* ws = (float*)d_ws;
    float* partial      = ws;                              // B*CHUNKS*D = 1,048,576 floats
    float* esum_partial = ws + BB * CHUNKS * DD;           // B*CHUNKS = 2048
    float* inv_esum     = esum_partial + BB * CHUNKS;      // B = 32

    logits_e_kernel<<<BB * SS / 4, 256, 0, stream>>>(
        (const float4*)keys, q, age, strength, logits, w);
    wsum_kernel<<<dim3(CHUNKS, BB), 128, 0, stream>>>(
        (const float4*)vals, w, (float4*)partial, esum_partial);
    reduce_rms_kernel<<<BB, 256, 0, stream>>>(partial, esum_partial, scale, readout, inv_esum);
    w_scale_kernel<<<BB * SS / 4 / 256, 256, 0, stream>>>((float4*)w, inv_esum);
}

// Round 6
// 176.719 us; speedup vs baseline: 1.2536x; 1.1416x over previous
//
#include <hip/hip_runtime.h>
#include <math.h>

#define BB 32
#define SS 8192
#define DD 512
#define D4 (DD / 4)   // 128
#define CHUNKS 64     // chunks per batch row
#define CHUNK 128     // slots per chunk (SS / CHUNKS)

static constexpr float AGE_PEN = 0.02f;
static constexpr float MIN_STR = 0.001f;
static constexpr float STR_BOOST = 0.5f;
static constexpr float RMS_EPS_F = 1e-6f;

typedef float vf4 __attribute__((ext_vector_type(4)));

__device__ inline float dot4v(vf4 a, vf4 b) {
    return a.x * b.x + a.y * b.y + a.z * b.z + a.w * b.w;
}

// block reduction (expects 256-thread block = 4 waves)
__device__ inline float block_sum(float v, volatile float* red) {
    int tid = threadIdx.x, lane = tid & 63, wid = tid >> 6;
#pragma unroll
    for (int off = 32; off; off >>= 1) v += __shfl_xor(v, off);
    if (lane == 0) red[wid] = v;
    __syncthreads();
    float r = red[0] + red[1] + red[2] + red[3];
    __syncthreads();
    return r;
}

// ---- kernel 1: keys stream -> logits + e. 4 rows per wave, 8 loads in flight ----
// grid = BB*SS/16 blocks, 256 threads (4 waves x 4 rows)
__global__ __launch_bounds__(256) void logits_e_kernel(
    const vf4* __restrict__ keys, const vf4* __restrict__ q,
    const vf4* __restrict__ age, const vf4* __restrict__ strength,
    vf4* __restrict__ logits4, vf4* __restrict__ e4) {
    int wid = threadIdx.x >> 6, lane = threadIdx.x & 63;
    int quad = blockIdx.x * 4 + wid;      // 4-row group index, < BB*SS/4
    int row0 = quad * 4;
    int b = row0 >> 13;                   // row0 / SS (quads never straddle b)

    // per-wave qn factor (q row = 2 KB, L1-hot; amortized over 4 rows)
    const vf4* qp = q + b * D4;
    vf4 q0 = qp[lane], q1 = qp[lane + 64];
    float qq = dot4v(q0, q0) + dot4v(q1, q1);
#pragma unroll
    for (int off = 32; off; off >>= 1) qq += __shfl_xor(qq, off);
    float qinv = 1.f / (sqrtf(qq) + 1e-6f);

    // issue all 8 key loads up-front (nontemporal: single-use stream)
    const vf4* k = keys + (long long)row0 * D4;
    vf4 ka0 = __builtin_nontemporal_load(k + lane);
    vf4 ka1 = __builtin_nontemporal_load(k + lane + 64);
    vf4 kb0 = __builtin_nontemporal_load(k + lane + 128);
    vf4 kb1 = __builtin_nontemporal_load(k + lane + 192);
    vf4 kc0 = __builtin_nontemporal_load(k + lane + 256);
    vf4 kc1 = __builtin_nontemporal_load(k + lane + 320);
    vf4 kd0 = __builtin_nontemporal_load(k + lane + 384);
    vf4 kd1 = __builtin_nontemporal_load(k + lane + 448);

    float kk0 = dot4v(ka0, ka0) + dot4v(ka1, ka1);
    float kq0 = dot4v(ka0, q0) + dot4v(ka1, q1);
    float kk1 = dot4v(kb0, kb0) + dot4v(kb1, kb1);
    float kq1 = dot4v(kb0, q0) + dot4v(kb1, q1);
    float kk2 = dot4v(kc0, kc0) + dot4v(kc1, kc1);
    float kq2 = dot4v(kc0, q0) + dot4v(kc1, q1);
    float kk3 = dot4v(kd0, kd0) + dot4v(kd1, kd1);
    float kq3 = dot4v(kd0, q0) + dot4v(kd1, q1);

#pragma unroll
    for (int off = 32; off; off >>= 1) {
        kk0 += __shfl_xor(kk0, off); kq0 += __shfl_xor(kq0, off);
        kk1 += __shfl_xor(kk1, off); kq1 += __shfl_xor(kq1, off);
        kk2 += __shfl_xor(kk2, off); kq2 += __shfl_xor(kq2, off);
        kk3 += __shfl_xor(kk3, off); kq3 += __shfl_xor(kq3, off);
    }

    // meta as vf4 (row0 is 16B-aligned); broadcast across lanes
    vf4 stv = strength[quad];
    vf4 agv = age[quad];

    float lg0 = kq0 * qinv / (sqrtf(kk0) + 1e-6f)
              + STR_BOOST * logf(fminf(fmaxf(stv.x, MIN_STR), 1e9f)) - AGE_PEN * agv.x;
    if (!(stv.x > MIN_STR)) lg0 -= 1000.f;
    float lg1 = kq1 * qinv / (sqrtf(kk1) + 1e-6f)
              + STR_BOOST * logf(fminf(fmaxf(stv.y, MIN_STR), 1e9f)) - AGE_PEN * agv.y;
    if (!(stv.y > MIN_STR)) lg1 -= 1000.f;
    float lg2 = kq2 * qinv / (sqrtf(kk2) + 1e-6f)
              + STR_BOOST * logf(fminf(fmaxf(stv.z, MIN_STR), 1e9f)) - AGE_PEN * agv.z;
    if (!(stv.z > MIN_STR)) lg2 -= 1000.f;
    float lg3 = kq3 * qinv / (sqrtf(kk3) + 1e-6f)
              + STR_BOOST * logf(fminf(fmaxf(stv.w, MIN_STR), 1e9f)) - AGE_PEN * agv.w;
    if (!(stv.w > MIN_STR)) lg3 -= 1000.f;

    if (lane == 0) {
        vf4 lgv; lgv.x = lg0; lgv.y = lg1; lgv.z = lg2; lgv.w = lg3;
        logits4[quad] = lgv;
        // logits <= 1: exp never overflows; dead slots underflow to 0
        vf4 ev; ev.x = expf(lg0); ev.y = expf(lg1); ev.z = expf(lg2); ev.w = expf(lg3);
        e4[quad] = ev;
    }
}

// ---- kernel 2: vals stream -> partial weighted sums + esum partials ----
// grid = (CHUNKS, B), 256 threads: column c = tid&127, row parity g = tid>>7
__global__ __launch_bounds__(256) void wsum_kernel(
    const vf4* __restrict__ vals, const float* __restrict__ e,
    vf4* __restrict__ partial, float* __restrict__ esum_partial) {
    __shared__ float sw[CHUNK];
    __shared__ vf4 racc[D4];
    __shared__ float rede[2];
    int chunk = blockIdx.x, b = blockIdx.y, tid = threadIdx.x;
    int c = tid & 127, g = tid >> 7;
    int s0 = chunk * CHUNK;

    if (tid < CHUNK) {
        float my_e = e[b * SS + s0 + tid];
        sw[tid] = my_e;
        float t = my_e;
#pragma unroll
        for (int off = 32; off; off >>= 1) t += __shfl_xor(t, off);
        if ((tid & 63) == 0) rede[tid >> 6] = t;
    }
    __syncthreads();
    if (tid == 0) esum_partial[b * CHUNKS + chunk] = rede[0] + rede[1];

    const vf4* vbase = vals + ((long long)b * SS + s0) * D4 + c;
    vf4 acc = {0.f, 0.f, 0.f, 0.f};
#pragma unroll 8
    for (int i = 0; i < CHUNK / 2; i++) {
        int s = 2 * i + g;
        vf4 v = __builtin_nontemporal_load(vbase + (long long)s * D4);
        acc += sw[s] * v;
    }
    if (g == 1) racc[c] = acc;
    __syncthreads();
    if (g == 0) {
        vf4 o = racc[c] + acc;
        partial[((long long)b * CHUNKS + chunk) * D4 + c] = o;
    }
}

// ---- kernel 3: reduce partials + esum, RMSNorm; one block per b ----
__global__ __launch_bounds__(256) void reduce_rms_kernel(
    const float* __restrict__ partial, const float* __restrict__ esum_partial,
    const float* __restrict__ scale, float* __restrict__ readout,
    float* __restrict__ inv_esum) {
    __shared__ float red[4];
    int b = blockIdx.x, tid = threadIdx.x;

    const float* p = partial + (long long)b * CHUNKS * DD;
    float r0 = 0.f, r1 = 0.f;
#pragma unroll 4
    for (int c = 0; c < CHUNKS; c++) {
        r0 += p[c * DD + tid];
        r1 += p[c * DD + tid + 256];
    }
    float le = (tid < CHUNKS) ? esum_partial[b * CHUNKS + tid] : 0.f;
    float etot = block_sum(le, red);
    float inv_e = 1.f / etot;
    if (tid == 0) inv_esum[b] = inv_e;
    r0 *= inv_e;
    r1 *= inv_e;
    float ss = block_sum(r0 * r0 + r1 * r1, red);
    float rms = sqrtf(ss / (float)DD + RMS_EPS_F);
    float inv = 1.f / rms;
    readout[b * DD + tid] = r0 * inv * scale[tid];
    readout[b * DD + tid + 256] = r1 * inv * scale[tid + 256];
}

// ---- kernel 4: w *= inv_esum[b], in place, vectorized ----
__global__ __launch_bounds__(256) void w_scale_kernel(vf4* __restrict__ w,
                                                      const float* __restrict__ inv_esum) {
    int i4 = blockIdx.x * 256 + threadIdx.x;  // BB*SS/4 = 65536 elems
    int b = i4 >> 11;                         // (i4*4) / SS
    float inv = inv_esum[b];
    w[i4] = w[i4] * inv;
}

extern "C" void kernel_launch(void* const* d_in, const int* in_sizes, int n_in,
                              void* d_out, int out_size, void* d_ws, size_t ws_size,
                              hipStream_t stream) {
    const float* q        = (const float*)d_in[0];
    const float* keys     = (const float*)d_in[1];
    const float* vals     = (const float*)d_in[2];
    const float* age      = (const float*)d_in[3];
    const float* strength = (const float*)d_in[4];
    const float* scale    = (const float*)d_in[5];

    float* out = (float*)d_out;
    float* readout = out;                      // [B, D]   = 16384
    float* w       = out + BB * DD;            // [B, S]   = 262144 (holds e, scaled in place)
    float* logits  = out + BB * DD + BB * SS;  // [B, S]   = 262144

    float* ws = (float*)d_ws;
    float* partial      = ws;                              // B*CHUNKS*D floats
    float* esum_partial = ws + BB * CHUNKS * DD;           // B*CHUNKS
    float* inv_esum     = esum_partial + BB * CHUNKS;      // B

    logits_e_kernel<<<BB * SS / 16, 256, 0, stream>>>(
        (const vf4*)keys, (const vf4*)q, (const vf4*)age, (const vf4*)strength,
        (vf4*)logits, (vf4*)w);
    wsum_kernel<<<dim3(CHUNKS, BB), 256, 0, stream>>>(
        (const vf4*)vals, w, (vf4*)partial, esum_partial);
    reduce_rms_kernel<<<BB, 256, 0, stream>>>(partial, esum_partial, scale, readout, inv_esum);
    w_scale_kernel<<<BB * SS / 4 / 256, 256, 0, stream>>>((vf4*)w, inv_esum);
}